// Round 1
// baseline (587.537 us; speedup 1.0000x reference)
//
#include <hip/hip_runtime.h>
#include <cfloat>
#include <type_traits>

#define C_DIM 256
#define HW    4096
#define NE    1024
#define NPIX  65536
#define KC    32
#define LSTR  132   // padded LDS row stride (floats)

// ---------------- ws layout ----------------
// offset 0     : float acc (loss accumulator)
// offset 256   : float e2[1024]
// offset 8192  : int   idx[65536]
// total ~264 KiB

// K1: ||e||^2 per codeword. One wave per codeword.
__global__ void e2_kernel(const float* __restrict__ cb, float* __restrict__ e2) {
  const int wave = (blockIdx.x * blockDim.x + threadIdx.x) >> 6;
  const int lane = threadIdx.x & 63;
  const float4 v = *(const float4*)(cb + (size_t)wave * C_DIM + lane * 4);
  float s = v.x * v.x + v.y * v.y + v.z * v.z + v.w * v.w;
  #pragma unroll
  for (int off = 32; off; off >>= 1) s += __shfl_down(s, off, 64);
  if (lane == 0) e2[wave] = s;
}

// K2: fused distance-GEMM + argmin.
// Block = 256 threads = 16 (n-dir) x 16 (p-dir); tile 128 codewords x 128 pixels,
// 8x8 register accumulators per thread. Loops 8 codeword chunks x K-slices of 32.
__global__ __launch_bounds__(256, 2)
void argmin_kernel(const float* __restrict__ z, const float* __restrict__ cb,
                   const float* __restrict__ e2, int* __restrict__ idx_out) {
  __shared__ float Elds[KC * LSTR];  // E transposed: [k][n], padded
  __shared__ float Zlds[KC * LSTR];  // Z: [k][p], padded

  const int tid = threadIdx.x;
  const int tn = tid & 15;        // codeword sub-tile
  const int tp = tid >> 4;        // pixel sub-tile
  const int ptile = blockIdx.x * 128;           // global pixel tile start
  const int b  = ptile >> 12;                   // batch (4096 pixels each; 128 | 4096)
  const int pb = ptile & 4095;                  // pixel offset within batch
  const float* zb = z + (size_t)b * C_DIM * HW + pb;

  float best_d[8];
  int   best_i[8];
  float zsq[8];
  #pragma unroll
  for (int j = 0; j < 8; ++j) { best_d[j] = FLT_MAX; best_i[j] = 0; zsq[j] = 0.f; }

  for (int nc = 0; nc < NE / 128; ++nc) {
    float acc[8][8];
    #pragma unroll
    for (int i = 0; i < 8; ++i)
      #pragma unroll
      for (int j = 0; j < 8; ++j) acc[i][j] = 0.f;

    auto kpass = [&](auto first_tag) {
      constexpr bool FIRST = decltype(first_tag)::value;
      for (int kc0 = 0; kc0 < C_DIM; kc0 += KC) {
        __syncthreads();  // previous slice's LDS reads done
        // --- stage E chunk (128n x 32k), transpose into [k][n] ---
        #pragma unroll
        for (int i = 0; i < 4; ++i) {
          const int id = i * 256 + tid;
          const int k4 = id & 7, nn = id >> 3;   // 8 lanes cover one row: coalesced 128B
          const float4 v = *(const float4*)(cb + (size_t)(nc * 128 + nn) * C_DIM + kc0 + k4 * 4);
          Elds[(k4 * 4 + 0) * LSTR + nn] = v.x;
          Elds[(k4 * 4 + 1) * LSTR + nn] = v.y;
          Elds[(k4 * 4 + 2) * LSTR + nn] = v.z;
          Elds[(k4 * 4 + 3) * LSTR + nn] = v.w;
        }
        // --- stage Z chunk (32k x 128p) ---
        #pragma unroll
        for (int i = 0; i < 4; ++i) {
          const int id = i * 256 + tid;
          const int p4 = id & 31, kk = id >> 5;  // 32 lanes cover one row: coalesced 512B
          const float4 v = *(const float4*)(zb + (size_t)(kc0 + kk) * HW + p4 * 4);
          *(float4*)&Zlds[kk * LSTR + p4 * 4] = v;
        }
        __syncthreads();
        // --- 8x8 outer-product FMA ---
        #pragma unroll 8
        for (int k = 0; k < KC; ++k) {
          const float4 e0 = *(const float4*)&Elds[k * LSTR + tn * 8];
          const float4 e1 = *(const float4*)&Elds[k * LSTR + tn * 8 + 4];
          const float4 z0 = *(const float4*)&Zlds[k * LSTR + tp * 8];
          const float4 z1 = *(const float4*)&Zlds[k * LSTR + tp * 8 + 4];
          const float ev[8] = {e0.x, e0.y, e0.z, e0.w, e1.x, e1.y, e1.z, e1.w};
          const float zv[8] = {z0.x, z0.y, z0.z, z0.w, z1.x, z1.y, z1.z, z1.w};
          if (FIRST) {
            #pragma unroll
            for (int j = 0; j < 8; ++j) zsq[j] = fmaf(zv[j], zv[j], zsq[j]);
          }
          #pragma unroll
          for (int i = 0; i < 8; ++i)
            #pragma unroll
            for (int j = 0; j < 8; ++j)
              acc[i][j] = fmaf(ev[i], zv[j], acc[i][j]);
        }
      }
    };
    if (nc == 0) kpass(std::true_type{}); else kpass(std::false_type{});

    // --- epilogue: d = (z^2 + e^2) - 2*dot, running argmin (first-occurrence ties) ---
    #pragma unroll
    for (int i = 0; i < 8; ++i) {
      const int n = nc * 128 + tn * 8 + i;
      const float ev2 = e2[n];
      #pragma unroll
      for (int j = 0; j < 8; ++j) {
        const float d = (zsq[j] + ev2) - 2.0f * acc[i][j];
        if (d < best_d[j] || (d == best_d[j] && n < best_i[j])) {
          best_d[j] = d; best_i[j] = n;
        }
      }
    }
  }

  // --- cross-thread (tn) reduction per pixel via LDS ---
  __syncthreads();
  float* red_d = Elds;
  int*   red_i = (int*)Zlds;
  #pragma unroll
  for (int j = 0; j < 8; ++j) {
    red_d[tn * LSTR + tp * 8 + j] = best_d[j];
    red_i[tn * LSTR + tp * 8 + j] = best_i[j];
  }
  __syncthreads();
  if (tid < 128) {
    float bd = red_d[tid];
    int   bi = red_i[tid];
    #pragma unroll
    for (int t = 1; t < 16; ++t) {
      const float d = red_d[t * LSTR + tid];
      const int  ii = red_i[t * LSTR + tid];
      if (d < bd || (d == bd && ii < bi)) { bd = d; bi = ii; }
    }
    idx_out[ptile + tid] = bi;
  }
}

// K3: gather zq into NCHW output + accumulate sum((zq - z)^2).
__global__ __launch_bounds__(256)
void gather_loss_kernel(const float* __restrict__ z, const float* __restrict__ cb,
                        const int* __restrict__ idx, float* __restrict__ out,
                        float* __restrict__ acc) {
  const int pg = blockIdx.x * 256 + threadIdx.x;
  const int b = pg >> 12, p = pg & 4095;
  const float* zrow = z   + (size_t)b * C_DIM * HW + p;
  float*       orow = out + (size_t)b * C_DIM * HW + p;
  const float* erow = cb + (size_t)idx[pg] * C_DIM;
  float s = 0.f;
  for (int c0 = 0; c0 < C_DIM; c0 += 4) {
    const float4 ev = *(const float4*)(erow + c0);   // L2-resident gather, 16B
    const float e[4] = {ev.x, ev.y, ev.z, ev.w};
    #pragma unroll
    for (int j = 0; j < 4; ++j) {
      const float zv = zrow[(size_t)(c0 + j) * HW];  // coalesced across lanes
      const float dd = e[j] - zv;
      s = fmaf(dd, dd, s);
      orow[(size_t)(c0 + j) * HW] = e[j];            // coalesced across lanes
    }
  }
  __shared__ float sdata[256];
  sdata[threadIdx.x] = s;
  __syncthreads();
  #pragma unroll
  for (int off = 128; off; off >>= 1) {
    if (threadIdx.x < off) sdata[threadIdx.x] += sdata[threadIdx.x + off];
    __syncthreads();
  }
  if (threadIdx.x == 0) atomicAdd(acc, sdata[0]);
}

// K4: loss = beta*mean + mean = 1.25 * sum / (B*C*H*W)
__global__ void finalize_kernel(const float* __restrict__ acc, float* __restrict__ loss_out) {
  *loss_out = 1.25f * (*acc) * (1.0f / 16777216.0f);
}

extern "C" void kernel_launch(void* const* d_in, const int* in_sizes, int n_in,
                              void* d_out, int out_size, void* d_ws, size_t ws_size,
                              hipStream_t stream) {
  const float* z  = (const float*)d_in[0];
  const float* cb = (const float*)d_in[1];
  float* out = (float*)d_out;

  float* acc = (float*)d_ws;
  float* e2  = (float*)((char*)d_ws + 256);
  int*   idx = (int*)((char*)d_ws + 8192);

  hipMemsetAsync(d_ws, 0, 256, stream);
  e2_kernel<<<NE / 4, 256, 0, stream>>>(cb, e2);
  argmin_kernel<<<NPIX / 128, 256, 0, stream>>>(z, cb, e2, idx);
  gather_loss_kernel<<<NPIX / 256, 256, 0, stream>>>(z, cb, idx, out, acc);
  finalize_kernel<<<1, 1, 0, stream>>>(acc, out + 16777216);
}

// Round 4
// 418.935 us; speedup vs baseline: 1.4025x; 1.4025x over previous
//
#include <hip/hip_runtime.h>
#include <cfloat>

#define C_DIM 256
#define HW    4096
#define NE    1024
#define NPIX  65536
#define TAU   1.0f
#define ZSTR  264   // ushorts per Z-LDS pixel row: 256 ch + pad (528 B, 16B-aligned, ≡4 mod 32 dwords)

typedef __attribute__((ext_vector_type(8))) short short8_t;
typedef __attribute__((ext_vector_type(8))) unsigned short ushort8_t;
typedef __attribute__((ext_vector_type(4))) float floatx4;

__device__ __forceinline__ unsigned short f2bf(float f) {
  unsigned int u = __float_as_uint(f);
  u += 0x7FFFu + ((u >> 16) & 1u);          // RNE; no NaN in this data
  return (unsigned short)(u >> 16);
}

// monotone float -> uint32 (for packed (d,idx) u64 min with lowest-index tie-break)
__device__ __forceinline__ unsigned int fenc(float f) {
  unsigned int u = __float_as_uint(f);
  return (u & 0x80000000u) ? ~u : (u | 0x80000000u);
}

// ---------------- ws layout ----------------
// @0       float acc (loss)            [zeroed per launch]
// @8       int   ccount                [zeroed per launch]
// @4096    float e2[1024]
// @8192    ushort Ebf[1024*256]        (512 KiB bf16 codebook)
// @532480  int   idx[65536]
// @794624  uchar flags[65536]
// @860160  u64   key64[65536]
// @1384448 int   clist[65536]

// K0: codebook -> bf16 copy + ||e||^2. One wave per codeword.
__global__ __launch_bounds__(256)
void prep_kernel(const float* __restrict__ cb, unsigned short* __restrict__ Ebf,
                 float* __restrict__ e2) {
  const int wave = (blockIdx.x * 256 + (int)threadIdx.x) >> 6;
  const int lane = threadIdx.x & 63;
  const float4 v = *(const float4*)(cb + (size_t)wave * C_DIM + lane * 4);
  ushort4 h;
  h.x = f2bf(v.x); h.y = f2bf(v.y); h.z = f2bf(v.z); h.w = f2bf(v.w);
  *(ushort4*)(Ebf + (size_t)wave * C_DIM + lane * 4) = h;
  float s = v.x * v.x + v.y * v.y + v.z * v.z + v.w * v.w;
  #pragma unroll
  for (int off = 32; off; off >>= 1) s += __shfl_down(s, off, 64);
  if (lane == 0) e2[wave] = s;
}

// K1: bf16 MFMA screen. Block = 4 waves, tile 128 px x 1024 cw (8 chunks of 128).
// Wave (wc,wp) owns 64 cw x 64 px = 4x4 grid of 16x16x32 MFMAs.
// Z staged ONCE (one barrier), A-frags streamed from L2-resident Ebf.
__global__ __launch_bounds__(256, 2)
void screen_kernel(const float* __restrict__ z, const unsigned short* __restrict__ Ebf,
                   const float* __restrict__ e2, int* __restrict__ idx_out,
                   unsigned char* __restrict__ flags, unsigned long long* __restrict__ key64,
                   int* __restrict__ clist, int* __restrict__ ccount) {
  __shared__ __align__(16) unsigned short Zl[128 * ZSTR];   // 67584 B... = 128*264*2 = 67584? no: 33792 B
  __shared__ float e2l[NE];

  const int tid = threadIdx.x;
  const int ptile = blockIdx.x * 128;
  const int b = ptile >> 12, pb = ptile & 4095;
  const float* zb = z + (size_t)b * (C_DIM * HW) + pb;

  // stage Z: z[k][p] fp32 -> Zl[p][k] bf16. Each thread: 8 coalesced scalar loads
  // (one pixel, 8 contiguous channels) -> one ds_write_b128. 2-way banks = free.
  #pragma unroll
  for (int it = 0; it < 16; ++it) {
    const int flat = it * 256 + tid;
    const int p = flat & 127, kb = flat >> 7;
    float f[8];
    #pragma unroll
    for (int j = 0; j < 8; ++j) f[j] = zb[(size_t)(kb * 8 + j) * HW + p];
    ushort8_t h;
    #pragma unroll
    for (int j = 0; j < 8; ++j) h[j] = f2bf(f[j]);
    *(ushort8_t*)&Zl[p * ZSTR + kb * 8] = h;
  }
  #pragma unroll
  for (int i = 0; i < 4; ++i) e2l[i * 256 + tid] = e2[i * 256 + tid];
  __syncthreads();

  const int lane = tid & 63;
  const int w = tid >> 6;
  const int wc = w & 1, wp = w >> 1;
  const int ln = lane & 15, quad = lane >> 4;

  float d1[4], d2[4]; int i1[4];
  #pragma unroll
  for (int j = 0; j < 4; ++j) { d1[j] = FLT_MAX; d2[j] = FLT_MAX; i1[j] = 0; }

  for (int nc = 0; nc < 8; ++nc) {
    const int cwb = nc * 128 + wc * 64;
    floatx4 acc[4][4];
    #pragma unroll
    for (int i = 0; i < 4; ++i)
      #pragma unroll
      for (int j = 0; j < 4; ++j) acc[i][j] = (floatx4){0.f, 0.f, 0.f, 0.f};

    #pragma unroll
    for (int ks = 0; ks < 8; ++ks) {
      short8_t a[4], bb[4];
      #pragma unroll
      for (int i = 0; i < 4; ++i)   // A[m=ln][k=quad*8+j]: 16B from Ebf row (L2-hot)
        a[i] = *(const short8_t*)(Ebf + (size_t)(cwb + i * 16 + ln) * C_DIM + ks * 32 + quad * 8);
      #pragma unroll
      for (int j = 0; j < 4; ++j)   // B[k=quad*8+j][n=ln]: 16B from Z row
        bb[j] = *(const short8_t*)(&Zl[(wp * 64 + j * 16 + ln) * ZSTR + ks * 32 + quad * 8]);
      #pragma unroll
      for (int i = 0; i < 4; ++i)
        #pragma unroll
        for (int j = 0; j < 4; ++j)
          acc[i][j] = __builtin_amdgcn_mfma_f32_16x16x32_bf16(a[i], bb[j], acc[i][j], 0, 0, 0);
    }

    // epilogue: d' = e2 - 2*dot; per-lane (d1,i1,d2). cw index ascending -> '<' keeps first.
    #pragma unroll
    for (int i = 0; i < 4; ++i) {
      const int cw0 = cwb + i * 16 + quad * 4;    // C/D: row = quad*4 + r (codeword)
      float ee[4];
      #pragma unroll
      for (int r = 0; r < 4; ++r) ee[r] = e2l[cw0 + r];
      #pragma unroll
      for (int j = 0; j < 4; ++j) {
        #pragma unroll
        for (int r = 0; r < 4; ++r) {
          const float d = fmaf(-2.0f, acc[i][j][r], ee[r]);
          const bool lt = d < d1[j];
          const float hi = lt ? d1[j] : d;
          d1[j] = lt ? d : d1[j];
          i1[j] = lt ? (cw0 + r) : i1[j];
          d2[j] = fminf(d2[j], hi);
        }
      }
    }
  }

  // cross-quad butterfly (lanes l, l^16, l^32 share pixel col = lane&15)
  #pragma unroll
  for (int j = 0; j < 4; ++j) {
    #pragma unroll
    for (int m = 16; m <= 32; m <<= 1) {
      const float od1 = __shfl_xor(d1[j], m, 64);
      const int   oi1 = __shfl_xor(i1[j], m, 64);
      const float od2 = __shfl_xor(d2[j], m, 64);
      const bool take = (od1 < d1[j]) || (od1 == d1[j] && oi1 < i1[j]);
      const float hi = take ? d1[j] : od1;
      d1[j] = take ? od1 : d1[j];
      i1[j] = take ? oi1 : i1[j];
      d2[j] = fminf(fminf(d2[j], od2), hi);
    }
  }

  // cross-wave (wc) merge via LDS (reuse Zl)
  __syncthreads();
  float* rd1 = (float*)Zl;
  int*   ri1 = (int*)Zl + 256;
  float* rd2 = (float*)Zl + 512;
  if (lane < 16) {
    #pragma unroll
    for (int j = 0; j < 4; ++j) {
      const int p = wp * 64 + j * 16 + ln;
      rd1[wc * 128 + p] = d1[j];
      ri1[wc * 128 + p] = i1[j];
      rd2[wc * 128 + p] = d2[j];
    }
  }
  __syncthreads();
  if (tid < 128) {
    const float a1 = rd1[tid], b1 = rd1[128 + tid];
    const int   ai = ri1[tid], bi = ri1[128 + tid];
    const float a2 = rd2[tid], b2 = rd2[128 + tid];
    const bool take = (b1 < a1) || (b1 == a1 && bi < ai);
    const float d1f = take ? b1 : a1;
    const int   i1f = take ? bi : ai;
    const float hi  = take ? a1 : b1;
    const float d2f = fminf(fminf(a2, b2), hi);
    const int gp = ptile + tid;
    idx_out[gp] = i1f;
    const bool contested = (d2f - d1f) <= TAU;   // screen error << TAU/2 -> else provably correct
    flags[gp] = contested ? 1 : 0;
    if (contested) {
      key64[gp] = ~0ULL;
      const int pos = atomicAdd(ccount, 1);
      clist[pos] = gp;
    }
  }
}

// K2: exact fp32 full rescan for contested pixels (groups of 8), packed-u64 atomicMin.
__global__ __launch_bounds__(256)
void rescan_kernel(const float* __restrict__ z, const float* __restrict__ cb,
                   const float* __restrict__ e2, const int* __restrict__ clist,
                   const int* __restrict__ ccount,
                   unsigned long long* __restrict__ key64) {
  __shared__ __align__(16) float zl[256 * 8];   // [k][px] -> broadcast reads
  __shared__ int pxs[8];
  __shared__ unsigned long long bestk[8];
  const int n = *ccount;
  const int ngroups = (n + 7) >> 3;
  for (int g = blockIdx.x; g < ngroups; g += gridDim.x) {
    const int base = g * 8;
    const int npx = min(8, n - base);
    if ((int)threadIdx.x < 8) {
      pxs[threadIdx.x] = clist[base + min((int)threadIdx.x, npx - 1)];  // pad with dup (idempotent)
      bestk[threadIdx.x] = ~0ULL;
    }
    __syncthreads();
    {
      const int k = threadIdx.x;
      float tmp[8];
      #pragma unroll
      for (int i = 0; i < 8; ++i) {
        const int gp = pxs[i];
        tmp[i] = z[(size_t)(gp >> 12) * (C_DIM * HW) + (size_t)k * HW + (gp & 4095)];
      }
      #pragma unroll
      for (int i = 0; i < 8; ++i) zl[k * 8 + i] = tmp[i];
    }
    __syncthreads();
    float dot[4][8];
    #pragma unroll
    for (int c = 0; c < 4; ++c)
      #pragma unroll
      for (int i = 0; i < 8; ++i) dot[c][i] = 0.f;
    for (int k0 = 0; k0 < 256; k0 += 4) {
      float ev[4][4];
      #pragma unroll
      for (int c = 0; c < 4; ++c)
        *(float4*)ev[c] = *(const float4*)(cb + (size_t)(c * 256 + threadIdx.x) * C_DIM + k0);
      float zz[4][8];
      #pragma unroll
      for (int kk = 0; kk < 4; ++kk) {
        *(float4*)&zz[kk][0] = *(const float4*)&zl[(k0 + kk) * 8];
        *(float4*)&zz[kk][4] = *(const float4*)&zl[(k0 + kk) * 8 + 4];
      }
      #pragma unroll
      for (int c = 0; c < 4; ++c)
        #pragma unroll
        for (int kk = 0; kk < 4; ++kk)
          #pragma unroll
          for (int i = 0; i < 8; ++i)
            dot[c][i] = fmaf(ev[c][kk], zz[kk][i], dot[c][i]);
    }
    unsigned long long mykey[8];
    #pragma unroll
    for (int i = 0; i < 8; ++i) mykey[i] = ~0ULL;
    #pragma unroll
    for (int c = 0; c < 4; ++c) {
      const int cw = c * 256 + threadIdx.x;
      const float ee = e2[cw];
      #pragma unroll
      for (int i = 0; i < 8; ++i) {
        const float d = fmaf(-2.0f, dot[c][i], ee);
        const unsigned long long key = ((unsigned long long)fenc(d) << 32) | (unsigned)cw;
        mykey[i] = mykey[i] < key ? mykey[i] : key;
      }
    }
    #pragma unroll
    for (int i = 0; i < 8; ++i) atomicMin(&bestk[i], mykey[i]);
    __syncthreads();
    if ((int)threadIdx.x < npx) atomicMin(&key64[pxs[threadIdx.x]], bestk[threadIdx.x]);
    __syncthreads();
  }
}

// K3: gather zq (NCHW) + loss sum, with contested-idx fixup.
__global__ __launch_bounds__(256)
void gather_loss_kernel(const float* __restrict__ z, const float* __restrict__ cb,
                        const int* __restrict__ idx, const unsigned char* __restrict__ flags,
                        const unsigned long long* __restrict__ key64,
                        float* __restrict__ out, float* __restrict__ acc) {
  const int pg = blockIdx.x * 256 + threadIdx.x;
  int id = idx[pg];
  if (flags[pg]) id = (int)(unsigned)(key64[pg] & 0xFFFFFFFFull);
  const int b = pg >> 12, p = pg & 4095;
  const float* zrow = z   + (size_t)b * (C_DIM * HW) + p;
  float*       orow = out + (size_t)b * (C_DIM * HW) + p;
  const float* erow = cb + (size_t)id * C_DIM;
  float s = 0.f;
  for (int c0 = 0; c0 < C_DIM; c0 += 4) {
    const float4 ev = *(const float4*)(erow + c0);
    const float e[4] = {ev.x, ev.y, ev.z, ev.w};
    #pragma unroll
    for (int j = 0; j < 4; ++j) {
      const float zv = zrow[(size_t)(c0 + j) * HW];
      const float dd = e[j] - zv;
      s = fmaf(dd, dd, s);
      orow[(size_t)(c0 + j) * HW] = e[j];
    }
  }
  __shared__ float sdata[256];
  sdata[threadIdx.x] = s;
  __syncthreads();
  #pragma unroll
  for (int off = 128; off; off >>= 1) {
    if (threadIdx.x < (unsigned)off) sdata[threadIdx.x] += sdata[threadIdx.x + off];
    __syncthreads();
  }
  if (threadIdx.x == 0) atomicAdd(acc, sdata[0]);
}

__global__ void finalize_kernel(const float* __restrict__ acc, float* __restrict__ loss_out) {
  *loss_out = 1.25f * (*acc) * (1.0f / 16777216.0f);
}

extern "C" void kernel_launch(void* const* d_in, const int* in_sizes, int n_in,
                              void* d_out, int out_size, void* d_ws, size_t ws_size,
                              hipStream_t stream) {
  const float* z  = (const float*)d_in[0];
  const float* cb = (const float*)d_in[1];
  float* out = (float*)d_out;
  char* ws = (char*)d_ws;

  float*              acc    = (float*)ws;
  int*                ccount = (int*)(ws + 8);
  float*              e2     = (float*)(ws + 4096);
  unsigned short*     Ebf    = (unsigned short*)(ws + 8192);
  int*                idx    = (int*)(ws + 532480);
  unsigned char*      flags  = (unsigned char*)(ws + 794624);
  unsigned long long* key64  = (unsigned long long*)(ws + 860160);
  int*                clist  = (int*)(ws + 1384448);

  (void)hipMemsetAsync(d_ws, 0, 16, stream);
  prep_kernel<<<NE / 4, 256, 0, stream>>>(cb, Ebf, e2);
  screen_kernel<<<NPIX / 128, 256, 0, stream>>>(z, Ebf, e2, idx, flags, key64, clist, ccount);
  rescan_kernel<<<1024, 256, 0, stream>>>(z, cb, e2, clist, ccount, key64);
  gather_loss_kernel<<<NPIX / 256, 256, 0, stream>>>(z, cb, idx, flags, key64, out, acc);
  finalize_kernel<<<1, 1, 0, stream>>>(acc, out + 16777216);
}

// Round 6
// 273.557 us; speedup vs baseline: 2.1478x; 1.5314x over previous
//
#include <hip/hip_runtime.h>
#include <cfloat>

#define C_DIM 256
#define HW    4096
#define NE    1024
#define NPIX  65536
#define TAU   0.15f
#define ZSTR  264   // fp16 per Z-LDS pixel row: 256 ch + 8 pad (528 B, 16B-aligned)

typedef __attribute__((ext_vector_type(8))) _Float16 half8_t;
typedef __attribute__((ext_vector_type(4))) _Float16 half4_t;
typedef __attribute__((ext_vector_type(4))) float floatx4;

// monotone float -> uint32 (for packed (d,idx) u64 min with lowest-index tie-break)
__device__ __forceinline__ unsigned int fenc(float f) {
  unsigned int u = __float_as_uint(f);
  return (u & 0x80000000u) ? ~u : (u | 0x80000000u);
}

// ---------------- ws layout (1.646 MB total — round-4-proven footprint) ----------------
// @0       float acc (loss)            [zeroed per launch]
// @8       int   ccount                [zeroed per launch]
// @4096    float e2[1024]
// @8192    _Float16 Ehf[1024*256]      (512 KiB fp16 codebook)
// @532480  int   idx[65536]
// @794624  uchar flags[65536]
// @860160  u64   key64[65536]
// @1384448 int   clist[65536]          (ends 1646592)

// K0: codebook -> fp16 copy + ||e||^2. One wave per codeword.
__global__ __launch_bounds__(256)
void prep_kernel(const float* __restrict__ cb, _Float16* __restrict__ Ehf,
                 float* __restrict__ e2) {
  const int wave = (blockIdx.x * 256 + (int)threadIdx.x) >> 6;
  const int lane = threadIdx.x & 63;
  const float4 v = *(const float4*)(cb + (size_t)wave * C_DIM + lane * 4);
  half4_t h;
  h.x = (_Float16)v.x; h.y = (_Float16)v.y; h.z = (_Float16)v.z; h.w = (_Float16)v.w;
  *(half4_t*)(Ehf + (size_t)wave * C_DIM + lane * 4) = h;
  float s = v.x * v.x + v.y * v.y + v.z * v.z + v.w * v.w;
  #pragma unroll
  for (int off = 32; off; off >>= 1) s += __shfl_down(s, off, 64);
  if (lane == 0) e2[wave] = s;
}

// K1: fp16 MFMA screen. Block = 4 waves, tile 128 px x 1024 cw (8 chunks of 128).
// Wave (wc,wp) owns 64 cw x 64 px = 4x4 grid of 16x16x32 MFMAs.
// Z staged ONCE (one barrier), A-frags streamed from L2-resident Ehf.
__global__ __launch_bounds__(256, 2)
void screen_kernel(const float* __restrict__ z, const _Float16* __restrict__ Ehf,
                   const float* __restrict__ e2, int* __restrict__ idx_out,
                   unsigned char* __restrict__ flags, unsigned long long* __restrict__ key64,
                   int* __restrict__ clist, int* __restrict__ ccount) {
  __shared__ __align__(16) _Float16 Zl[128 * ZSTR];   // 67584 B
  __shared__ float e2l[NE];                           // 4096 B

  const int tid = threadIdx.x;
  const int ptile = blockIdx.x * 128;
  const int b = ptile >> 12, pb = ptile & 4095;
  const float* zb = z + (size_t)b * (C_DIM * HW) + pb;

  // stage Z: z[k][p] fp32 -> Zl[p][k] fp16. Each thread: 8 coalesced scalar loads
  // (one pixel, 8 contiguous channels) -> one ds_write_b128.
  #pragma unroll
  for (int it = 0; it < 16; ++it) {
    const int flat = it * 256 + tid;
    const int p = flat & 127, kb = flat >> 7;
    float f[8];
    #pragma unroll
    for (int j = 0; j < 8; ++j) f[j] = zb[(size_t)(kb * 8 + j) * HW + p];
    half8_t h;
    #pragma unroll
    for (int j = 0; j < 8; ++j) h[j] = (_Float16)f[j];
    *(half8_t*)&Zl[p * ZSTR + kb * 8] = h;
  }
  #pragma unroll
  for (int i = 0; i < 4; ++i) e2l[i * 256 + tid] = e2[i * 256 + tid];
  __syncthreads();

  const int lane = tid & 63;
  const int w = tid >> 6;
  const int wc = w & 1, wp = w >> 1;
  const int ln = lane & 15, quad = lane >> 4;

  float d1[4], d2[4]; int i1[4];
  #pragma unroll
  for (int j = 0; j < 4; ++j) { d1[j] = FLT_MAX; d2[j] = FLT_MAX; i1[j] = 0; }

  for (int nc = 0; nc < 8; ++nc) {
    const int cwb = nc * 128 + wc * 64;
    floatx4 acc[4][4];
    #pragma unroll
    for (int i = 0; i < 4; ++i)
      #pragma unroll
      for (int j = 0; j < 4; ++j) acc[i][j] = (floatx4){0.f, 0.f, 0.f, 0.f};

    #pragma unroll
    for (int ks = 0; ks < 8; ++ks) {
      half8_t a[4], bb[4];
      #pragma unroll
      for (int i = 0; i < 4; ++i)   // A[m=ln][k=quad*8+j]: 16B from Ehf row (L2-hot)
        a[i] = *(const half8_t*)(Ehf + (size_t)(cwb + i * 16 + ln) * C_DIM + ks * 32 + quad * 8);
      #pragma unroll
      for (int j = 0; j < 4; ++j)   // B[k=quad*8+j][n=ln]: 16B from Z row
        bb[j] = *(const half8_t*)(&Zl[(wp * 64 + j * 16 + ln) * ZSTR + ks * 32 + quad * 8]);
      #pragma unroll
      for (int i = 0; i < 4; ++i)
        #pragma unroll
        for (int j = 0; j < 4; ++j)
          acc[i][j] = __builtin_amdgcn_mfma_f32_16x16x32_f16(a[i], bb[j], acc[i][j], 0, 0, 0);
    }

    // epilogue: d' = e2 - 2*dot; per-lane (d1,i1,d2). cw index ascending -> '<' keeps first.
    #pragma unroll
    for (int i = 0; i < 4; ++i) {
      const int cw0 = cwb + i * 16 + quad * 4;    // C/D: row = quad*4 + r (codeword)
      float ee[4];
      #pragma unroll
      for (int r = 0; r < 4; ++r) ee[r] = e2l[cw0 + r];
      #pragma unroll
      for (int j = 0; j < 4; ++j) {
        #pragma unroll
        for (int r = 0; r < 4; ++r) {
          const float d = fmaf(-2.0f, acc[i][j][r], ee[r]);
          const bool lt = d < d1[j];
          const float hi = lt ? d1[j] : d;
          d1[j] = lt ? d : d1[j];
          i1[j] = lt ? (cw0 + r) : i1[j];
          d2[j] = fminf(d2[j], hi);
        }
      }
    }
  }

  // cross-quad butterfly (lanes l, l^16, l^32 share pixel col = lane&15)
  #pragma unroll
  for (int j = 0; j < 4; ++j) {
    #pragma unroll
    for (int m = 16; m <= 32; m <<= 1) {
      const float od1 = __shfl_xor(d1[j], m, 64);
      const int   oi1 = __shfl_xor(i1[j], m, 64);
      const float od2 = __shfl_xor(d2[j], m, 64);
      const bool take = (od1 < d1[j]) || (od1 == d1[j] && oi1 < i1[j]);
      const float hi = take ? d1[j] : od1;
      d1[j] = take ? od1 : d1[j];
      i1[j] = take ? oi1 : i1[j];
      d2[j] = fminf(fminf(d2[j], od2), hi);
    }
  }

  // cross-wave (wc) merge via LDS (reuse Zl)
  __syncthreads();
  float* rd1 = (float*)Zl;
  int*   ri1 = (int*)Zl + 256;
  float* rd2 = (float*)Zl + 512;
  if (lane < 16) {
    #pragma unroll
    for (int j = 0; j < 4; ++j) {
      const int p = wp * 64 + j * 16 + ln;
      rd1[wc * 128 + p] = d1[j];
      ri1[wc * 128 + p] = i1[j];
      rd2[wc * 128 + p] = d2[j];
    }
  }
  __syncthreads();
  if (tid < 128) {
    const float a1 = rd1[tid], b1 = rd1[128 + tid];
    const int   ai = ri1[tid], bi = ri1[128 + tid];
    const float a2 = rd2[tid], b2 = rd2[128 + tid];
    const bool take = (b1 < a1) || (b1 == a1 && bi < ai);
    const float d1f = take ? b1 : a1;
    const int   i1f = take ? bi : ai;
    const float hi  = take ? a1 : b1;
    const float d2f = fminf(fminf(a2, b2), hi);
    const int gp = ptile + tid;
    idx_out[gp] = i1f;
    const bool contested = (d2f - d1f) <= TAU;   // fp16 gap error sigma ~3e-2; TAU = 5 sigma
    flags[gp] = contested ? 1 : 0;
    if (contested) {
      key64[gp] = ~0ULL;
      const int pos = atomicAdd(ccount, 1);
      clist[pos] = gp;
    }
  }
}

// K2: exact fp32 full rescan for contested pixels (groups of 8), packed-u64 atomicMin.
__global__ __launch_bounds__(256)
void rescan_kernel(const float* __restrict__ z, const float* __restrict__ cb,
                   const float* __restrict__ e2, const int* __restrict__ clist,
                   const int* __restrict__ ccount,
                   unsigned long long* __restrict__ key64) {
  __shared__ __align__(16) float zl[256 * 8];   // [k][px] -> broadcast reads
  __shared__ int pxs[8];
  __shared__ unsigned long long bestk[8];
  const int n = *ccount;
  const int ngroups = (n + 7) >> 3;
  for (int g = blockIdx.x; g < ngroups; g += gridDim.x) {
    const int base = g * 8;
    const int npx = min(8, n - base);
    if ((int)threadIdx.x < 8) {
      pxs[threadIdx.x] = clist[base + min((int)threadIdx.x, npx - 1)];  // pad with dup (idempotent)
      bestk[threadIdx.x] = ~0ULL;
    }
    __syncthreads();
    {
      const int k = threadIdx.x;
      float tmp[8];
      #pragma unroll
      for (int i = 0; i < 8; ++i) {
        const int gp = pxs[i];
        tmp[i] = z[(size_t)(gp >> 12) * (C_DIM * HW) + (size_t)k * HW + (gp & 4095)];
      }
      #pragma unroll
      for (int i = 0; i < 8; ++i) zl[k * 8 + i] = tmp[i];
    }
    __syncthreads();
    float dot[4][8];
    #pragma unroll
    for (int c = 0; c < 4; ++c)
      #pragma unroll
      for (int i = 0; i < 8; ++i) dot[c][i] = 0.f;
    for (int k0 = 0; k0 < 256; k0 += 4) {
      float ev[4][4];
      #pragma unroll
      for (int c = 0; c < 4; ++c)
        *(float4*)ev[c] = *(const float4*)(cb + (size_t)(c * 256 + threadIdx.x) * C_DIM + k0);
      float zz[4][8];
      #pragma unroll
      for (int kk = 0; kk < 4; ++kk) {
        *(float4*)&zz[kk][0] = *(const float4*)&zl[(k0 + kk) * 8];
        *(float4*)&zz[kk][4] = *(const float4*)&zl[(k0 + kk) * 8 + 4];
      }
      #pragma unroll
      for (int c = 0; c < 4; ++c)
        #pragma unroll
        for (int kk = 0; kk < 4; ++kk)
          #pragma unroll
          for (int i = 0; i < 8; ++i)
            dot[c][i] = fmaf(ev[c][kk], zz[kk][i], dot[c][i]);
    }
    unsigned long long mykey[8];
    #pragma unroll
    for (int i = 0; i < 8; ++i) mykey[i] = ~0ULL;
    #pragma unroll
    for (int c = 0; c < 4; ++c) {
      const int cw = c * 256 + threadIdx.x;
      const float ee = e2[cw];
      #pragma unroll
      for (int i = 0; i < 8; ++i) {
        const float d = fmaf(-2.0f, dot[c][i], ee);
        const unsigned long long key = ((unsigned long long)fenc(d) << 32) | (unsigned)cw;
        mykey[i] = mykey[i] < key ? mykey[i] : key;
      }
    }
    #pragma unroll
    for (int i = 0; i < 8; ++i) atomicMin(&bestk[i], mykey[i]);
    __syncthreads();
    if ((int)threadIdx.x < npx) atomicMin(&key64[pxs[threadIdx.x]], bestk[threadIdx.x]);
    __syncthreads();
  }
}

// K3: gather zq (NCHW) + loss sum, with contested-idx fixup.
__global__ __launch_bounds__(256)
void gather_loss_kernel(const float* __restrict__ z, const float* __restrict__ cb,
                        const int* __restrict__ idx, const unsigned char* __restrict__ flags,
                        const unsigned long long* __restrict__ key64,
                        float* __restrict__ out, float* __restrict__ acc) {
  const int pg = blockIdx.x * 256 + threadIdx.x;
  int id = idx[pg];
  if (flags[pg]) id = (int)(unsigned)(key64[pg] & 0xFFFFFFFFull);
  const int b = pg >> 12, p = pg & 4095;
  const float* zrow = z   + (size_t)b * (C_DIM * HW) + p;
  float*       orow = out + (size_t)b * (C_DIM * HW) + p;
  const float* erow = cb + (size_t)id * C_DIM;
  float s = 0.f;
  for (int c0 = 0; c0 < C_DIM; c0 += 4) {
    const float4 ev = *(const float4*)(erow + c0);
    const float e[4] = {ev.x, ev.y, ev.z, ev.w};
    #pragma unroll
    for (int j = 0; j < 4; ++j) {
      const float zv = zrow[(size_t)(c0 + j) * HW];
      const float dd = e[j] - zv;
      s = fmaf(dd, dd, s);
      orow[(size_t)(c0 + j) * HW] = e[j];
    }
  }
  __shared__ float sdata[256];
  sdata[threadIdx.x] = s;
  __syncthreads();
  #pragma unroll
  for (int off = 128; off; off >>= 1) {
    if (threadIdx.x < (unsigned)off) sdata[threadIdx.x] += sdata[threadIdx.x + off];
    __syncthreads();
  }
  if (threadIdx.x == 0) atomicAdd(acc, sdata[0]);
}

__global__ void finalize_kernel(const float* __restrict__ acc, float* __restrict__ loss_out) {
  *loss_out = 1.25f * (*acc) * (1.0f / 16777216.0f);
}

extern "C" void kernel_launch(void* const* d_in, const int* in_sizes, int n_in,
                              void* d_out, int out_size, void* d_ws, size_t ws_size,
                              hipStream_t stream) {
  const float* z  = (const float*)d_in[0];
  const float* cb = (const float*)d_in[1];
  float* out = (float*)d_out;
  char* ws = (char*)d_ws;

  float*              acc    = (float*)ws;
  int*                ccount = (int*)(ws + 8);
  float*              e2     = (float*)(ws + 4096);
  _Float16*           Ehf    = (_Float16*)(ws + 8192);
  int*                idx    = (int*)(ws + 532480);
  unsigned char*      flags  = (unsigned char*)(ws + 794624);
  unsigned long long* key64  = (unsigned long long*)(ws + 860160);
  int*                clist  = (int*)(ws + 1384448);

  (void)hipMemsetAsync(d_ws, 0, 16, stream);
  prep_kernel<<<NE / 4, 256, 0, stream>>>(cb, Ehf, e2);
  screen_kernel<<<NPIX / 128, 256, 0, stream>>>(z, Ehf, e2, idx, flags, key64, clist, ccount);
  rescan_kernel<<<1024, 256, 0, stream>>>(z, cb, e2, clist, ccount, key64);
  gather_loss_kernel<<<NPIX / 256, 256, 0, stream>>>(z, cb, idx, flags, key64, out, acc);
  finalize_kernel<<<1, 1, 0, stream>>>(acc, out + 16777216);
}

// Round 7
// 256.116 us; speedup vs baseline: 2.2940x; 1.0681x over previous
//
#include <hip/hip_runtime.h>
#include <cfloat>

#define C_DIM 256
#define HW    4096
#define NE    1024
#define NPIX  65536
#define TAU   0.15f
#define ZSTR  264   // fp16 per Z-LDS pixel row: 256 ch + 8 pad (528 B, 16B-aligned)

typedef __attribute__((ext_vector_type(8))) _Float16 half8_t;
typedef __attribute__((ext_vector_type(4))) _Float16 half4_t;
typedef __attribute__((ext_vector_type(4))) float floatx4;

// monotone float -> uint32 (for packed (d,idx) u64 min with lowest-index tie-break)
__device__ __forceinline__ unsigned int fenc(float f) {
  unsigned int u = __float_as_uint(f);
  return (u & 0x80000000u) ? ~u : (u | 0x80000000u);
}

// ---------------- ws layout (1.646 MB total — round-4-proven footprint) ----------------
// @0       float acc (loss)            [zeroed per launch]
// @8       int   ccount                [zeroed per launch]
// @4096    float e2[1024]
// @8192    _Float16 Ehf[1024*256]      (512 KiB fp16 codebook)
// @532480  int   idx[65536]
// @794624  uchar flags[65536]
// @860160  u64   key64[65536]
// @1384448 int   clist[65536]          (ends 1646592)

// K0: codebook -> fp16 copy + ||e||^2. One wave per codeword.
__global__ __launch_bounds__(256)
void prep_kernel(const float* __restrict__ cb, _Float16* __restrict__ Ehf,
                 float* __restrict__ e2) {
  const int wave = (blockIdx.x * 256 + (int)threadIdx.x) >> 6;
  const int lane = threadIdx.x & 63;
  const float4 v = *(const float4*)(cb + (size_t)wave * C_DIM + lane * 4);
  half4_t h;
  h.x = (_Float16)v.x; h.y = (_Float16)v.y; h.z = (_Float16)v.z; h.w = (_Float16)v.w;
  *(half4_t*)(Ehf + (size_t)wave * C_DIM + lane * 4) = h;
  float s = v.x * v.x + v.y * v.y + v.z * v.z + v.w * v.w;
  #pragma unroll
  for (int off = 32; off; off >>= 1) s += __shfl_down(s, off, 64);
  if (lane == 0) e2[wave] = s;
}

// K1: fp16 MFMA screen with software-pipelined A/B fragment prefetch.
// Block = 4 waves, tile 128 px x 1024 cw (8 chunks of 128).
// Wave (wc,wp) owns 64 cw x 64 px = 4x4 grid of 16x16x32 MFMAs.
// Z staged ONCE (one barrier), A-frags double-buffered from L2-resident Ehf.
__global__ __launch_bounds__(256, 2)
void screen_kernel(const float* __restrict__ z, const _Float16* __restrict__ Ehf,
                   const float* __restrict__ e2, int* __restrict__ idx_out,
                   unsigned char* __restrict__ flags, unsigned long long* __restrict__ key64,
                   int* __restrict__ clist, int* __restrict__ ccount) {
  __shared__ __align__(16) _Float16 Zl[128 * ZSTR];   // 67584 B
  __shared__ float e2l[NE];                           // 4096 B

  const int tid = threadIdx.x;
  const int ptile = blockIdx.x * 128;
  const int b = ptile >> 12, pb = ptile & 4095;
  const float* zb = z + (size_t)b * (C_DIM * HW) + pb;

  // stage Z: z[k][p] fp32 -> Zl[p][k] fp16. Each thread: 8 coalesced scalar loads
  // (one pixel, 8 contiguous channels) -> one ds_write_b128.
  #pragma unroll
  for (int it = 0; it < 16; ++it) {
    const int flat = it * 256 + tid;
    const int p = flat & 127, kb = flat >> 7;
    float f[8];
    #pragma unroll
    for (int j = 0; j < 8; ++j) f[j] = zb[(size_t)(kb * 8 + j) * HW + p];
    half8_t h;
    #pragma unroll
    for (int j = 0; j < 8; ++j) h[j] = (_Float16)f[j];
    *(half8_t*)&Zl[p * ZSTR + kb * 8] = h;
  }
  #pragma unroll
  for (int i = 0; i < 4; ++i) e2l[i * 256 + tid] = e2[i * 256 + tid];
  __syncthreads();

  const int lane = tid & 63;
  const int w = tid >> 6;
  const int wc = w & 1, wp = w >> 1;
  const int ln = lane & 15, quad = lane >> 4;

  // precomputed fragment row pointers (i/j-indexed); per-step byte offsets added below
  const char* rowA[4];
  const char* rowB[4];
  #pragma unroll
  for (int i = 0; i < 4; ++i)
    rowA[i] = (const char*)(Ehf + (size_t)(wc * 64 + i * 16 + ln) * C_DIM + quad * 8);
  #pragma unroll
  for (int j = 0; j < 4; ++j)
    rowB[j] = (const char*)(&Zl[(wp * 64 + j * 16 + ln) * ZSTR + quad * 8]);

  float d1[4], d2[4]; int i1[4];
  #pragma unroll
  for (int j = 0; j < 4; ++j) { d1[j] = FLT_MAX; d2[j] = FLT_MAX; i1[j] = 0; }

  half8_t abuf[2][4], bbuf[2][4];
  // prologue: load fragments for step 0 (nc=0, ks=0)
  #pragma unroll
  for (int i = 0; i < 4; ++i) abuf[0][i] = *(const half8_t*)(rowA[i]);
  #pragma unroll
  for (int j = 0; j < 4; ++j) bbuf[0][j] = *(const half8_t*)(rowB[j]);

  for (int nc = 0; nc < 8; ++nc) {
    floatx4 acc[4][4];
    #pragma unroll
    for (int i = 0; i < 4; ++i)
      #pragma unroll
      for (int j = 0; j < 4; ++j) acc[i][j] = (floatx4){0.f, 0.f, 0.f, 0.f};

    #pragma unroll
    for (int ks = 0; ks < 8; ++ks) {
      const int cur = ks & 1, nxt = cur ^ 1;
      // prefetch step+1 (wraps harmlessly past the last step: reads stay inside ws)
      const int nstep = nc * 8 + ks + 1;
      const size_t aoff = (size_t)(nstep >> 3) * (128 * C_DIM * 2) + (size_t)(nstep & 7) * 64;
      const size_t boff = (size_t)(nstep & 7) * 64;
      #pragma unroll
      for (int i = 0; i < 4; ++i) abuf[nxt][i] = *(const half8_t*)(rowA[i] + aoff);
      #pragma unroll
      for (int j = 0; j < 4; ++j) bbuf[nxt][j] = *(const half8_t*)(rowB[j] + boff);
      // compute on current buffers (independent of the prefetch)
      #pragma unroll
      for (int i = 0; i < 4; ++i)
        #pragma unroll
        for (int j = 0; j < 4; ++j)
          acc[i][j] = __builtin_amdgcn_mfma_f32_16x16x32_f16(abuf[cur][i], bbuf[cur][j], acc[i][j], 0, 0, 0);
    }

    // epilogue: d' = e2 - 2*dot; per-lane (d1,i1,d2). cw index ascending -> '<' keeps first.
    const int cwb = nc * 128 + wc * 64;
    #pragma unroll
    for (int i = 0; i < 4; ++i) {
      const int cw0 = cwb + i * 16 + quad * 4;    // C/D: row = quad*4 + r (codeword)
      float ee[4];
      #pragma unroll
      for (int r = 0; r < 4; ++r) ee[r] = e2l[cw0 + r];
      #pragma unroll
      for (int j = 0; j < 4; ++j) {
        #pragma unroll
        for (int r = 0; r < 4; ++r) {
          const float d = fmaf(-2.0f, acc[i][j][r], ee[r]);
          const bool lt = d < d1[j];
          const float hi = lt ? d1[j] : d;
          d1[j] = lt ? d : d1[j];
          i1[j] = lt ? (cw0 + r) : i1[j];
          d2[j] = fminf(d2[j], hi);
        }
      }
    }
  }

  // cross-quad butterfly (lanes l, l^16, l^32 share pixel col = lane&15)
  #pragma unroll
  for (int j = 0; j < 4; ++j) {
    #pragma unroll
    for (int m = 16; m <= 32; m <<= 1) {
      const float od1 = __shfl_xor(d1[j], m, 64);
      const int   oi1 = __shfl_xor(i1[j], m, 64);
      const float od2 = __shfl_xor(d2[j], m, 64);
      const bool take = (od1 < d1[j]) || (od1 == d1[j] && oi1 < i1[j]);
      const float hi = take ? d1[j] : od1;
      d1[j] = take ? od1 : d1[j];
      i1[j] = take ? oi1 : i1[j];
      d2[j] = fminf(fminf(d2[j], od2), hi);
    }
  }

  // cross-wave (wc) merge via LDS (reuse Zl)
  __syncthreads();
  float* rd1 = (float*)Zl;
  int*   ri1 = (int*)Zl + 256;
  float* rd2 = (float*)Zl + 512;
  if (lane < 16) {
    #pragma unroll
    for (int j = 0; j < 4; ++j) {
      const int p = wp * 64 + j * 16 + ln;
      rd1[wc * 128 + p] = d1[j];
      ri1[wc * 128 + p] = i1[j];
      rd2[wc * 128 + p] = d2[j];
    }
  }
  __syncthreads();
  if (tid < 128) {
    const float a1 = rd1[tid], b1 = rd1[128 + tid];
    const int   ai = ri1[tid], bi = ri1[128 + tid];
    const float a2 = rd2[tid], b2 = rd2[128 + tid];
    const bool take = (b1 < a1) || (b1 == a1 && bi < ai);
    const float d1f = take ? b1 : a1;
    const int   i1f = take ? bi : ai;
    const float hi  = take ? a1 : b1;
    const float d2f = fminf(fminf(a2, b2), hi);
    const int gp = ptile + tid;
    idx_out[gp] = i1f;
    const bool contested = (d2f - d1f) <= TAU;   // fp16 gap error sigma ~3e-2; TAU = 5 sigma
    flags[gp] = contested ? 1 : 0;
    if (contested) {
      key64[gp] = ~0ULL;
      const int pos = atomicAdd(ccount, 1);
      clist[pos] = gp;
    }
  }
}

// K2: exact fp32 rescan for contested pixels. Work unit = (group of 8 px) x (octant
// of 128 codewords): 8 blocks cooperate per group via device-scope atomicMin(key64).
__global__ __launch_bounds__(256)
void rescan_kernel(const float* __restrict__ z, const float* __restrict__ cb,
                   const float* __restrict__ e2, const int* __restrict__ clist,
                   const int* __restrict__ ccount,
                   unsigned long long* __restrict__ key64) {
  __shared__ __align__(16) float zl[256 * 8];   // [k][px] -> broadcast reads
  __shared__ int pxs[8];
  __shared__ unsigned long long bestk[8];
  const int n = *ccount;
  const int ngroups = (n + 7) >> 3;
  const int nunits = ngroups * 8;
  for (int u = blockIdx.x; u < nunits; u += gridDim.x) {
    const int g = u >> 3, oct = u & 7;
    const int base = g * 8;
    const int npx = min(8, n - base);
    if ((int)threadIdx.x < 8) {
      pxs[threadIdx.x] = clist[base + min((int)threadIdx.x, npx - 1)];  // pad with dup (idempotent)
      bestk[threadIdx.x] = ~0ULL;
    }
    __syncthreads();
    {
      const int k = threadIdx.x;
      float tmp[8];
      #pragma unroll
      for (int i = 0; i < 8; ++i) {
        const int gp = pxs[i];
        tmp[i] = z[(size_t)(gp >> 12) * (C_DIM * HW) + (size_t)k * HW + (gp & 4095)];
      }
      #pragma unroll
      for (int i = 0; i < 8; ++i) zl[k * 8 + i] = tmp[i];
    }
    __syncthreads();
    // thread t: codeword cw = oct*128 + (t&127); pixel half ph = t>>7 (4 px each)
    const int cw = oct * 128 + ((int)threadIdx.x & 127);
    const int ph = (int)threadIdx.x >> 7;
    const float* row = cb + (size_t)cw * C_DIM;
    float dot[4] = {0.f, 0.f, 0.f, 0.f};
    for (int k0 = 0; k0 < 256; k0 += 4) {
      const float4 ev = *(const float4*)(row + k0);     // 128 distinct rows, L2-hot
      const float e4[4] = {ev.x, ev.y, ev.z, ev.w};
      #pragma unroll
      for (int kk = 0; kk < 4; ++kk) {
        const float4 zz = *(const float4*)&zl[(k0 + kk) * 8 + ph * 4];  // broadcast
        dot[0] = fmaf(e4[kk], zz.x, dot[0]);
        dot[1] = fmaf(e4[kk], zz.y, dot[1]);
        dot[2] = fmaf(e4[kk], zz.z, dot[2]);
        dot[3] = fmaf(e4[kk], zz.w, dot[3]);
      }
    }
    const float ee = e2[cw];
    #pragma unroll
    for (int i = 0; i < 4; ++i) {
      const float d = fmaf(-2.0f, dot[i], ee);
      const unsigned long long key = ((unsigned long long)fenc(d) << 32) | (unsigned)cw;
      atomicMin(&bestk[ph * 4 + i], key);
    }
    __syncthreads();
    if ((int)threadIdx.x < npx) atomicMin(&key64[pxs[threadIdx.x]], bestk[threadIdx.x]);
    __syncthreads();
  }
}

// K3: gather zq (NCHW) + loss sum, with contested-idx fixup.
__global__ __launch_bounds__(256)
void gather_loss_kernel(const float* __restrict__ z, const float* __restrict__ cb,
                        const int* __restrict__ idx, const unsigned char* __restrict__ flags,
                        const unsigned long long* __restrict__ key64,
                        float* __restrict__ out, float* __restrict__ acc) {
  const int pg = blockIdx.x * 256 + threadIdx.x;
  int id = idx[pg];
  if (flags[pg]) id = (int)(unsigned)(key64[pg] & 0xFFFFFFFFull);
  const int b = pg >> 12, p = pg & 4095;
  const float* zrow = z   + (size_t)b * (C_DIM * HW) + p;
  float*       orow = out + (size_t)b * (C_DIM * HW) + p;
  const float* erow = cb + (size_t)id * C_DIM;
  float s = 0.f;
  for (int c0 = 0; c0 < C_DIM; c0 += 4) {
    const float4 ev = *(const float4*)(erow + c0);
    const float e[4] = {ev.x, ev.y, ev.z, ev.w};
    #pragma unroll
    for (int j = 0; j < 4; ++j) {
      const float zv = zrow[(size_t)(c0 + j) * HW];
      const float dd = e[j] - zv;
      s = fmaf(dd, dd, s);
      orow[(size_t)(c0 + j) * HW] = e[j];
    }
  }
  __shared__ float sdata[256];
  sdata[threadIdx.x] = s;
  __syncthreads();
  #pragma unroll
  for (int off = 128; off; off >>= 1) {
    if (threadIdx.x < (unsigned)off) sdata[threadIdx.x] += sdata[threadIdx.x + off];
    __syncthreads();
  }
  if (threadIdx.x == 0) atomicAdd(acc, sdata[0]);
}

__global__ void finalize_kernel(const float* __restrict__ acc, float* __restrict__ loss_out) {
  *loss_out = 1.25f * (*acc) * (1.0f / 16777216.0f);
}

extern "C" void kernel_launch(void* const* d_in, const int* in_sizes, int n_in,
                              void* d_out, int out_size, void* d_ws, size_t ws_size,
                              hipStream_t stream) {
  const float* z  = (const float*)d_in[0];
  const float* cb = (const float*)d_in[1];
  float* out = (float*)d_out;
  char* ws = (char*)d_ws;

  float*              acc    = (float*)ws;
  int*                ccount = (int*)(ws + 8);
  float*              e2     = (float*)(ws + 4096);
  _Float16*           Ehf    = (_Float16*)(ws + 8192);
  int*                idx    = (int*)(ws + 532480);
  unsigned char*      flags  = (unsigned char*)(ws + 794624);
  unsigned long long* key64  = (unsigned long long*)(ws + 860160);
  int*                clist  = (int*)(ws + 1384448);

  (void)hipMemsetAsync(d_ws, 0, 16, stream);
  prep_kernel<<<NE / 4, 256, 0, stream>>>(cb, Ehf, e2);
  screen_kernel<<<NPIX / 128, 256, 0, stream>>>(z, Ehf, e2, idx, flags, key64, clist, ccount);
  rescan_kernel<<<1024, 256, 0, stream>>>(z, cb, e2, clist, ccount, key64);
  gather_loss_kernel<<<NPIX / 256, 256, 0, stream>>>(z, cb, idx, flags, key64, out, acc);
  finalize_kernel<<<1, 1, 0, stream>>>(acc, out + 16777216);
}

// Round 8
// 237.895 us; speedup vs baseline: 2.4697x; 1.0766x over previous
//
#include <hip/hip_runtime.h>
#include <cfloat>

#define C_DIM 256
#define HW    4096
#define NE    1024
#define NPIX  65536
#define TAU   0.15f
#define ZSTR  264   // fp16 per Z-LDS pixel row: 256 ch + 8 pad (528 B, 16B-aligned)

typedef __attribute__((ext_vector_type(8))) _Float16 half8_t;
typedef __attribute__((ext_vector_type(4))) float floatx4;

// monotone float -> uint32 (for packed (d,idx) u64 min with lowest-index tie-break)
__device__ __forceinline__ unsigned int fenc(float f) {
  unsigned int u = __float_as_uint(f);
  return (u & 0x80000000u) ? ~u : (u | 0x80000000u);
}

// ---------------- ws layout (1.646 MB total — round-4-proven footprint) ----------------
// @0       float acc (loss)            [zeroed per launch]
// @8       int   ccount                [zeroed per launch]
// @4096    float e2[1024]
// @8192    _Float16 EhfP[1024*256]     (512 KiB fp16 codebook, MFMA-fragment-packed)
// @532480  int   idx[65536]
// @794624  uchar flags[65536]
// @860160  u64   key64[65536]
// @1384448 int   clist[65536]          (ends 1646592)

// K0a: ||e||^2 per codeword. One wave per codeword.
__global__ __launch_bounds__(256)
void e2_kernel(const float* __restrict__ cb, float* __restrict__ e2) {
  const int wave = (blockIdx.x * 256 + (int)threadIdx.x) >> 6;
  const int lane = threadIdx.x & 63;
  const float4 v = *(const float4*)(cb + (size_t)wave * C_DIM + lane * 4);
  float s = v.x * v.x + v.y * v.y + v.z * v.z + v.w * v.w;
  #pragma unroll
  for (int off = 32; off; off >>= 1) s += __shfl_down(s, off, 64);
  if (lane == 0) e2[wave] = s;
}

// K0b: pack codebook into MFMA A-fragment order.
// EhfP[g][ks][i][lane] (16B each): lane l=(quad<<4|ln) holds cb[g*64+i*16+ln][ks*32+quad*8 .. +8].
// Screen's A-load becomes base + lane*16 — fully coalesced 1 KiB per fragment.
__global__ __launch_bounds__(256)
void pack_kernel(const float* __restrict__ cb, _Float16* __restrict__ EhfP) {
  const int g = blockIdx.x >> 3, it = blockIdx.x & 7;
  const int sidx = it * 256 + (int)threadIdx.x;       // (ks*256 + i*64 + lane)
  const int ks = sidx >> 8, i = (sidx >> 6) & 3, lane = sidx & 63;
  const int ln = lane & 15, quad = lane >> 4;
  const float* src = cb + (size_t)(g * 64 + i * 16 + ln) * C_DIM + ks * 32 + quad * 8;
  const float4 v0 = *(const float4*)(src);
  const float4 v1 = *(const float4*)(src + 4);
  half8_t h;
  h[0] = (_Float16)v0.x; h[1] = (_Float16)v0.y; h[2] = (_Float16)v0.z; h[3] = (_Float16)v0.w;
  h[4] = (_Float16)v1.x; h[5] = (_Float16)v1.y; h[6] = (_Float16)v1.z; h[7] = (_Float16)v1.w;
  *(half8_t*)(EhfP + (size_t)g * 16384 + (size_t)sidx * 8) = h;
}

// K1: fp16 MFMA screen, A from fragment-packed codebook (coalesced), A/B double-buffered.
// Block = 4 waves, tile 128 px x 1024 cw (8 chunks of 128).
// Wave (wc,wp) owns 64 cw x 64 px = 4x4 grid of 16x16x32 MFMAs.
__global__ __launch_bounds__(256, 2)
void screen_kernel(const float* __restrict__ z, const _Float16* __restrict__ EhfP,
                   const float* __restrict__ e2, int* __restrict__ idx_out,
                   unsigned char* __restrict__ flags, unsigned long long* __restrict__ key64,
                   int* __restrict__ clist, int* __restrict__ ccount) {
  __shared__ __align__(16) _Float16 Zl[128 * ZSTR];   // 67584 B
  __shared__ float e2l[NE];                           // 4096 B

  const int tid = threadIdx.x;
  const int ptile = blockIdx.x * 128;
  const int b = ptile >> 12, pb = ptile & 4095;
  const float* zb = z + (size_t)b * (C_DIM * HW) + pb;

  // stage Z: z[k][p] fp32 -> Zl[p][k] fp16. Each thread: 8 coalesced scalar loads
  // (one pixel, 8 contiguous channels) -> one ds_write_b128.
  #pragma unroll
  for (int it = 0; it < 16; ++it) {
    const int flat = it * 256 + tid;
    const int p = flat & 127, kb = flat >> 7;
    float f[8];
    #pragma unroll
    for (int j = 0; j < 8; ++j) f[j] = zb[(size_t)(kb * 8 + j) * HW + p];
    half8_t h;
    #pragma unroll
    for (int j = 0; j < 8; ++j) h[j] = (_Float16)f[j];
    *(half8_t*)&Zl[p * ZSTR + kb * 8] = h;
  }
  #pragma unroll
  for (int i = 0; i < 4; ++i) e2l[i * 256 + tid] = e2[i * 256 + tid];
  __syncthreads();

  const int lane = tid & 63;
  const int w = tid >> 6;
  const int wc = w & 1, wp = w >> 1;
  const int ln = lane & 15, quad = lane >> 4;

  // A stream: wave wc's fragments for chunk nc at EhfP + (nc*2+wc)*16384 halves;
  // step (nc,ks), frag i: + ks*2048 + i*512 + lane*8 halves (16B/lane, coalesced).
  const _Float16* aBase = EhfP + (size_t)wc * 16384 + (size_t)lane * 8;
  const char* rowB[4];
  #pragma unroll
  for (int j = 0; j < 4; ++j)
    rowB[j] = (const char*)(&Zl[(wp * 64 + j * 16 + ln) * ZSTR + quad * 8]);

  float d1[4], d2[4]; int i1[4];
  #pragma unroll
  for (int j = 0; j < 4; ++j) { d1[j] = FLT_MAX; d2[j] = FLT_MAX; i1[j] = 0; }

  half8_t abuf[2][4], bbuf[2][4];
  // prologue: fragments for step 0 (nc=0, ks=0)
  #pragma unroll
  for (int i = 0; i < 4; ++i) abuf[0][i] = *(const half8_t*)(aBase + i * 512);
  #pragma unroll
  for (int j = 0; j < 4; ++j) bbuf[0][j] = *(const half8_t*)(rowB[j]);

  for (int nc = 0; nc < 8; ++nc) {
    floatx4 acc[4][4];
    #pragma unroll
    for (int i = 0; i < 4; ++i)
      #pragma unroll
      for (int j = 0; j < 4; ++j) acc[i][j] = (floatx4){0.f, 0.f, 0.f, 0.f};

    #pragma unroll
    for (int ks = 0; ks < 8; ++ks) {
      const int cur = ks & 1, nxt = cur ^ 1;
      // prefetch step s+1 (clamped to last step: redundant reload, in-bounds)
      const int s1 = nc * 8 + ks + 1;
      const int sp = s1 > 63 ? 63 : s1;
      const size_t aoff = (size_t)(sp >> 3) * 32768 + (size_t)(sp & 7) * 2048;
      const int bks = sp & 7;
      #pragma unroll
      for (int i = 0; i < 4; ++i) abuf[nxt][i] = *(const half8_t*)(aBase + aoff + i * 512);
      #pragma unroll
      for (int j = 0; j < 4; ++j) bbuf[nxt][j] = *(const half8_t*)(rowB[j] + bks * 64);
      // compute on current buffers
      #pragma unroll
      for (int i = 0; i < 4; ++i)
        #pragma unroll
        for (int j = 0; j < 4; ++j)
          acc[i][j] = __builtin_amdgcn_mfma_f32_16x16x32_f16(abuf[cur][i], bbuf[cur][j], acc[i][j], 0, 0, 0);
    }

    // epilogue: d' = e2 - 2*dot; per-lane (d1,i1,d2). cw index ascending -> '<' keeps first.
    const int cwb = nc * 128 + wc * 64;
    #pragma unroll
    for (int i = 0; i < 4; ++i) {
      const int cw0 = cwb + i * 16 + quad * 4;    // C/D: row = quad*4 + r (codeword)
      float ee[4];
      #pragma unroll
      for (int r = 0; r < 4; ++r) ee[r] = e2l[cw0 + r];
      #pragma unroll
      for (int j = 0; j < 4; ++j) {
        #pragma unroll
        for (int r = 0; r < 4; ++r) {
          const float d = fmaf(-2.0f, acc[i][j][r], ee[r]);
          const bool lt = d < d1[j];
          const float hi = lt ? d1[j] : d;
          d1[j] = lt ? d : d1[j];
          i1[j] = lt ? (cw0 + r) : i1[j];
          d2[j] = fminf(d2[j], hi);
        }
      }
    }
  }

  // cross-quad butterfly (lanes l, l^16, l^32 share pixel col = lane&15)
  #pragma unroll
  for (int j = 0; j < 4; ++j) {
    #pragma unroll
    for (int m = 16; m <= 32; m <<= 1) {
      const float od1 = __shfl_xor(d1[j], m, 64);
      const int   oi1 = __shfl_xor(i1[j], m, 64);
      const float od2 = __shfl_xor(d2[j], m, 64);
      const bool take = (od1 < d1[j]) || (od1 == d1[j] && oi1 < i1[j]);
      const float hi = take ? d1[j] : od1;
      d1[j] = take ? od1 : d1[j];
      i1[j] = take ? oi1 : i1[j];
      d2[j] = fminf(fminf(d2[j], od2), hi);
    }
  }

  // cross-wave (wc) merge via LDS (reuse Zl)
  __syncthreads();
  float* rd1 = (float*)Zl;
  int*   ri1 = (int*)Zl + 256;
  float* rd2 = (float*)Zl + 512;
  if (lane < 16) {
    #pragma unroll
    for (int j = 0; j < 4; ++j) {
      const int p = wp * 64 + j * 16 + ln;
      rd1[wc * 128 + p] = d1[j];
      ri1[wc * 128 + p] = i1[j];
      rd2[wc * 128 + p] = d2[j];
    }
  }
  __syncthreads();
  if (tid < 128) {
    const float a1 = rd1[tid], b1 = rd1[128 + tid];
    const int   ai = ri1[tid], bi = ri1[128 + tid];
    const float a2 = rd2[tid], b2 = rd2[128 + tid];
    const bool take = (b1 < a1) || (b1 == a1 && bi < ai);
    const float d1f = take ? b1 : a1;
    const int   i1f = take ? bi : ai;
    const float hi  = take ? a1 : b1;
    const float d2f = fminf(fminf(a2, b2), hi);
    const int gp = ptile + tid;
    idx_out[gp] = i1f;
    const bool contested = (d2f - d1f) <= TAU;   // fp16 gap error sigma ~3e-2; TAU = 5 sigma
    flags[gp] = contested ? 1 : 0;
    if (contested) {
      key64[gp] = ~0ULL;
      const int pos = atomicAdd(ccount, 1);
      clist[pos] = gp;
    }
  }
}

// K2: exact fp32 rescan for contested pixels. Work unit = (group of 8 px) x (octant
// of 128 codewords): 8 blocks cooperate per group via device-scope atomicMin(key64).
__global__ __launch_bounds__(256)
void rescan_kernel(const float* __restrict__ z, const float* __restrict__ cb,
                   const float* __restrict__ e2, const int* __restrict__ clist,
                   const int* __restrict__ ccount,
                   unsigned long long* __restrict__ key64) {
  __shared__ __align__(16) float zl[256 * 8];   // [k][px] -> broadcast reads
  __shared__ int pxs[8];
  __shared__ unsigned long long bestk[8];
  const int n = *ccount;
  const int ngroups = (n + 7) >> 3;
  const int nunits = ngroups * 8;
  for (int u = blockIdx.x; u < nunits; u += gridDim.x) {
    const int g = u >> 3, oct = u & 7;
    const int base = g * 8;
    const int npx = min(8, n - base);
    if ((int)threadIdx.x < 8) {
      pxs[threadIdx.x] = clist[base + min((int)threadIdx.x, npx - 1)];  // pad with dup (idempotent)
      bestk[threadIdx.x] = ~0ULL;
    }
    __syncthreads();
    {
      const int k = threadIdx.x;
      float tmp[8];
      #pragma unroll
      for (int i = 0; i < 8; ++i) {
        const int gp = pxs[i];
        tmp[i] = z[(size_t)(gp >> 12) * (C_DIM * HW) + (size_t)k * HW + (gp & 4095)];
      }
      #pragma unroll
      for (int i = 0; i < 8; ++i) zl[k * 8 + i] = tmp[i];
    }
    __syncthreads();
    // thread t: codeword cw = oct*128 + (t&127); pixel half ph = t>>7 (4 px each)
    const int cw = oct * 128 + ((int)threadIdx.x & 127);
    const int ph = (int)threadIdx.x >> 7;
    const float* row = cb + (size_t)cw * C_DIM;
    float dot[4] = {0.f, 0.f, 0.f, 0.f};
    for (int k0 = 0; k0 < 256; k0 += 4) {
      const float4 ev = *(const float4*)(row + k0);     // 128 distinct rows, L2-hot
      const float e4[4] = {ev.x, ev.y, ev.z, ev.w};
      #pragma unroll
      for (int kk = 0; kk < 4; ++kk) {
        const float4 zz = *(const float4*)&zl[(k0 + kk) * 8 + ph * 4];  // broadcast
        dot[0] = fmaf(e4[kk], zz.x, dot[0]);
        dot[1] = fmaf(e4[kk], zz.y, dot[1]);
        dot[2] = fmaf(e4[kk], zz.z, dot[2]);
        dot[3] = fmaf(e4[kk], zz.w, dot[3]);
      }
    }
    const float ee = e2[cw];
    #pragma unroll
    for (int i = 0; i < 4; ++i) {
      const float d = fmaf(-2.0f, dot[i], ee);
      const unsigned long long key = ((unsigned long long)fenc(d) << 32) | (unsigned)cw;
      atomicMin(&bestk[ph * 4 + i], key);
    }
    __syncthreads();
    if ((int)threadIdx.x < npx) atomicMin(&key64[pxs[threadIdx.x]], bestk[threadIdx.x]);
    __syncthreads();
  }
}

// K3: gather zq (NCHW) + loss sum, with contested-idx fixup.
__global__ __launch_bounds__(256)
void gather_loss_kernel(const float* __restrict__ z, const float* __restrict__ cb,
                        const int* __restrict__ idx, const unsigned char* __restrict__ flags,
                        const unsigned long long* __restrict__ key64,
                        float* __restrict__ out, float* __restrict__ acc) {
  const int pg = blockIdx.x * 256 + threadIdx.x;
  int id = idx[pg];
  if (flags[pg]) id = (int)(unsigned)(key64[pg] & 0xFFFFFFFFull);
  const int b = pg >> 12, p = pg & 4095;
  const float* zrow = z   + (size_t)b * (C_DIM * HW) + p;
  float*       orow = out + (size_t)b * (C_DIM * HW) + p;
  const float* erow = cb + (size_t)id * C_DIM;
  float s = 0.f;
  for (int c0 = 0; c0 < C_DIM; c0 += 4) {
    const float4 ev = *(const float4*)(erow + c0);
    const float e[4] = {ev.x, ev.y, ev.z, ev.w};
    #pragma unroll
    for (int j = 0; j < 4; ++j) {
      const float zv = zrow[(size_t)(c0 + j) * HW];
      const float dd = e[j] - zv;
      s = fmaf(dd, dd, s);
      orow[(size_t)(c0 + j) * HW] = e[j];
    }
  }
  __shared__ float sdata[256];
  sdata[threadIdx.x] = s;
  __syncthreads();
  #pragma unroll
  for (int off = 128; off; off >>= 1) {
    if (threadIdx.x < (unsigned)off) sdata[threadIdx.x] += sdata[threadIdx.x + off];
    __syncthreads();
  }
  if (threadIdx.x == 0) atomicAdd(acc, sdata[0]);
}

__global__ void finalize_kernel(const float* __restrict__ acc, float* __restrict__ loss_out) {
  *loss_out = 1.25f * (*acc) * (1.0f / 16777216.0f);
}

extern "C" void kernel_launch(void* const* d_in, const int* in_sizes, int n_in,
                              void* d_out, int out_size, void* d_ws, size_t ws_size,
                              hipStream_t stream) {
  const float* z  = (const float*)d_in[0];
  const float* cb = (const float*)d_in[1];
  float* out = (float*)d_out;
  char* ws = (char*)d_ws;

  float*              acc    = (float*)ws;
  int*                ccount = (int*)(ws + 8);
  float*              e2     = (float*)(ws + 4096);
  _Float16*           EhfP   = (_Float16*)(ws + 8192);
  int*                idx    = (int*)(ws + 532480);
  unsigned char*      flags  = (unsigned char*)(ws + 794624);
  unsigned long long* key64  = (unsigned long long*)(ws + 860160);
  int*                clist  = (int*)(ws + 1384448);

  (void)hipMemsetAsync(d_ws, 0, 16, stream);
  e2_kernel<<<NE / 4, 256, 0, stream>>>(cb, e2);
  pack_kernel<<<128, 256, 0, stream>>>(cb, EhfP);
  screen_kernel<<<NPIX / 128, 256, 0, stream>>>(z, EhfP, e2, idx, flags, key64, clist, ccount);
  rescan_kernel<<<1024, 256, 0, stream>>>(z, cb, e2, clist, ccount, key64);
  gather_loss_kernel<<<NPIX / 256, 256, 0, stream>>>(z, cb, idx, flags, key64, out, acc);
  finalize_kernel<<<1, 1, 0, stream>>>(acc, out + 16777216);
}